// Round 4
// baseline (81.347 us; speedup 1.0000x reference)
//
#include <hip/hip_runtime.h>
#include <hip/hip_bf16.h>
#include <stdint.h>

#define MB_ 16384
#define NN_ 1024
#define KK_ 1024

typedef __bf16 bhalf;
typedef __bf16 bhalf8 __attribute__((ext_vector_type(8)));
typedef __bf16 bhalf4 __attribute__((ext_vector_type(4)));
typedef float f32x4 __attribute__((ext_vector_type(4)));

typedef const __attribute__((address_space(1))) void* gas_ptr;
typedef __attribute__((address_space(3))) void* las_ptr;

__device__ __forceinline__ void gload_lds16(const void* g, void* l) {
  __builtin_amdgcn_global_load_lds((gas_ptr)g, (las_ptr)l, 16, 0, 0);
}

// ---------------- K1a: partial column max / sumexp (over rows, per column) ----------------
__global__ void k_colpart(const float* __restrict__ W,
                          float* __restrict__ pM, float* __restrict__ pS) {
  int col = blockIdx.x * 256 + threadIdx.x;
  int rc  = blockIdx.y;
  const float* p = W + (size_t)rc * 32 * NN_ + col;
  float v[32];
#pragma unroll
  for (int i = 0; i < 32; ++i) v[i] = p[(size_t)i * NN_];
  float m = v[0];
#pragma unroll
  for (int i = 1; i < 32; ++i) m = fmaxf(m, v[i]);
  float s = 0.f;
#pragma unroll
  for (int i = 0; i < 32; ++i) s += __expf(v[i] - m);
  pM[rc * NN_ + col] = m;
  pS[rc * NN_ + col] = s;
}

// ---------------- K1b: combine partials -> colLSE ----------------
__global__ void k_colfin(const float* __restrict__ pM, const float* __restrict__ pS,
                         float* __restrict__ colLSE) {
  int col = blockIdx.x * 256 + threadIdx.x;
  float m = -1e30f;
#pragma unroll
  for (int i = 0; i < 32; ++i) m = fmaxf(m, pM[i * NN_ + col]);
  float s = 0.f;
#pragma unroll
  for (int i = 0; i < 32; ++i) s += pS[i * NN_ + col] * __expf(pM[i * NN_ + col] - m);
  colLSE[col] = m + __logf(s);
}

// ---------------- K2: eA[i,k] = exp(W[i,k]-colLSE[k])  (no mA shift needed) ----------------
__global__ void k_expA(const float* __restrict__ W, const float* __restrict__ colLSE,
                       bhalf* __restrict__ eA) {
  int i = blockIdx.x;
  int l = threadIdx.x;
  const float4* row = (const float4*)(W + (size_t)i * NN_);
  const float4* cls = (const float4*)colLSE;
#pragma unroll
  for (int t = 0; t < 4; ++t) {
    float4 wv = row[t * 64 + l];
    float4 cv = cls[t * 64 + l];
    bhalf4 o;
    o[0] = (bhalf)__expf(wv.x - cv.x);
    o[1] = (bhalf)__expf(wv.y - cv.y);
    o[2] = (bhalf)__expf(wv.z - cv.z);
    o[3] = (bhalf)__expf(wv.w - cv.w);
    *(bhalf4*)(eA + (size_t)i * NN_ + t * 256 + l * 4) = o;
  }
}

// ---------------- GEMM: out[b,i] = log( sum_k exp(la[b,k]) * eA[i,k] ) ----------------
// 256x256 tile, BK=64, 512 thr (8 waves 2Mx4N).
// A (exp(la)) is REG-STAGED with fused exp: 8x dwordx4 f32 at q0 -> vmcnt post-MFMA(q3)
//   -> exp+pack bf16 -> 4 swizzled ds_write_b128.  B (eA) uses global_load_lds with
//   pre-swizzled source, staged 2 tiles ahead.
// LDS: A dbuf [0,64K) (32KB each), B dbuf [64K,128K).
// vmcnt(4) post-MFMA q3: outstanding = [A-regs(t+1)(8), B(t+2)(4)] -> waits A(t+1)
// (and any older B(t+1)), leaves B(t+2) in flight across the barrier.

#define VMW(N)  asm volatile("s_waitcnt vmcnt(" #N ")" ::: "memory")
#define LGKM0   asm volatile("s_waitcnt lgkmcnt(0)" ::: "memory")
#define HINT8   asm volatile("s_waitcnt lgkmcnt(8)" ::: "memory")
#define SBAR    __builtin_amdgcn_s_barrier()
#define SCB0    __builtin_amdgcn_sched_barrier(0)

#define STB(BUF, H, TOFF) do {                                                \
    const bhalf* g_ = pgB + (H) * 131072 + (TOFF) * 64;                       \
    unsigned char* d_ = lds + 65536 + (BUF) * 32768 + (H) * 16384 + tid * 16; \
    gload_lds16(g_, d_); gload_lds16(g_ + 65536, d_ + 8192); } while (0)

#define LOADA(TOFF) do {                                                      \
    _Pragma("unroll")                                                         \
    for (int j_ = 0; j_ < 8; ++j_) va[j_] = pLA4[(TOFF) * 16 + j_]; } while (0)

#define CVTA(BUF) do {                                                        \
    unsigned char* d_ = dA_base + (BUF) * 32768;                              \
    _Pragma("unroll")                                                         \
    for (int j_ = 0; j_ < 4; ++j_) {                                          \
      float4 u_ = va[2 * j_], w_ = va[2 * j_ + 1];                            \
      bhalf8 o_;                                                              \
      o_[0] = (bhalf)__expf(u_.x); o_[1] = (bhalf)__expf(u_.y);               \
      o_[2] = (bhalf)__expf(u_.z); o_[3] = (bhalf)__expf(u_.w);               \
      o_[4] = (bhalf)__expf(w_.x); o_[5] = (bhalf)__expf(w_.y);               \
      o_[6] = (bhalf)__expf(w_.z); o_[7] = (bhalf)__expf(w_.w);               \
      *(bhalf8*)(d_ + dOff[j_]) = o_;                                         \
    } } while (0)

#define DS_AF(BUF, Q)                                                         \
  af[0][0] = *(const bhalf8*)(pA0 + (BUF) * 32768 + (Q) * 4096);              \
  af[0][1] = *(const bhalf8*)(pA1 + (BUF) * 32768 + (Q) * 4096);              \
  af[1][0] = *(const bhalf8*)(pA0 + (BUF) * 32768 + (Q) * 4096 + 2048);       \
  af[1][1] = *(const bhalf8*)(pA1 + (BUF) * 32768 + (Q) * 4096 + 2048);

#define DS_BQ(BUF)                                                            \
  _Pragma("unroll")                                                           \
  for (int n_ = 0; n_ < 4; ++n_) {                                            \
    bq[n_][0] = *(const bhalf8*)(pB0 + (BUF) * 32768 + n_ * 2048);            \
    bq[n_][1] = *(const bhalf8*)(pB1 + (BUF) * 32768 + n_ * 2048);            \
  }

#define MFMA8(Q)                                                              \
  __builtin_amdgcn_s_setprio(1);                                              \
  _Pragma("unroll")                                                           \
  for (int m_ = 0; m_ < 2; ++m_)                                              \
    _Pragma("unroll")                                                         \
    for (int n_ = 0; n_ < 4; ++n_)                                            \
      _Pragma("unroll")                                                       \
      for (int kk_ = 0; kk_ < 2; ++kk_)                                       \
        acc[2 * (Q) + m_][n_] = __builtin_amdgcn_mfma_f32_16x16x32_bf16(      \
            af[m_][kk_], bq[n_][kk_], acc[2 * (Q) + m_][n_], 0, 0, 0);        \
  __builtin_amdgcn_s_setprio(0);

#define HEAD  SCB0; SBAR; LGKM0; SCB0

// LT: A-load k-tile offset (f32 source), -1 = none. BT: B-stage k-tile offset, -1 = none.
// VMN: 4 / 0 / -1 (post-MFMA q3 wait). A(t+1) is cvt+written to buf BUF^1.
#define KTILE(BUF, LT, BT, VMN)                                               \
  {                                                                           \
    bhalf8 bq[4][2];                                                          \
    bhalf8 af[2][2];                                                          \
    DS_AF(BUF, 0) DS_BQ(BUF)                                                  \
    if ((LT) >= 0) LOADA(LT);                                                 \
    HINT8;                                                                    \
    HEAD; MFMA8(0) SBAR;                                                      \
    DS_AF(BUF, 1)                                                             \
    if ((BT) >= 0) STB(BUF, 0, BT);                                           \
    HEAD; MFMA8(1) SBAR;                                                      \
    DS_AF(BUF, 2)                                                             \
    if ((BT) >= 0) STB(BUF, 1, BT);                                           \
    HEAD; MFMA8(2) SBAR;                                                      \
    DS_AF(BUF, 3)                                                             \
    HEAD; MFMA8(3)                                                            \
    if ((VMN) == 4) VMW(4); else if ((VMN) == 0) VMW(0);                      \
    if ((LT) >= 0) { CVTA((BUF) ^ 1); LGKM0; }                                \
    SCB0; SBAR;                                                               \
  }

__global__ __launch_bounds__(512, 2) void k_gemm(const float* __restrict__ LA, // [M][K] f32
                                                 const bhalf* __restrict__ Bt, // eA [N][K]
                                                 float* __restrict__ out) {
  __shared__ __align__(16) unsigned char lds[131072];

  const int nwg = gridDim.x;              // 256, %8==0
  const int wg  = blockIdx.x;
  const int swz = (wg & 7) * (nwg >> 3) + (wg >> 3);
  const int bm = swz >> 2;                // 0..63
  const int bn = swz & 3;                 // 0..3

  const int tid = threadIdx.x;
  const int l = tid & 63;
  const int w = tid >> 6;
  const int wr = w >> 2;                  // 0..1 (M)
  const int wc = w & 3;                   // 0..3 (N)

  // B staging geometry (gload_lds, linear dest, pre-swizzled source)
  const int r8  = tid >> 3;
  const int kel = (((tid & 7) ^ (r8 & 7)) << 3);
  const bhalf* pgB = Bt + (size_t)(bn * 256 + r8) * KK_ + kel;

  // A reg-staging geometry: thread covers row ar (0..255), chunks ac0..ac0+3
  const int ar  = tid >> 1;
  const int ac0 = (tid & 1) * 4;
  const float4* pLA4 = (const float4*)(LA + (size_t)(bm * 256 + ar) * KK_ + ac0 * 8);
  unsigned char* dA_base = lds + (ar >> 7) * 16384 + (ar & 127) * 128;
  int dOff[4];
#pragma unroll
  for (int j = 0; j < 4; ++j) dOff[j] = ((ac0 + j) ^ (ar & 7)) * 16;

  // loop-invariant LDS read bases (fragment row % 8 == l % 8)
  const int kx  = 16 * (l >> 4);
  const int x16 = (l & 7) << 4;
  const int kx0 = kx ^ x16;
  const int kx1 = (64 + kx) ^ x16;
  const unsigned char* pA0 = lds + wr * 16384 + (l & 15) * 128 + kx0;
  const unsigned char* pA1 = lds + wr * 16384 + (l & 15) * 128 + kx1;
  const unsigned char* pB0 = lds + 65536 + (wc >> 1) * 16384 + ((wc & 1) * 64 + (l & 15)) * 128 + kx0;
  const unsigned char* pB1 = lds + 65536 + (wc >> 1) * 16384 + ((wc & 1) * 64 + (l & 15)) * 128 + kx1;

  f32x4 zero = {0.f, 0.f, 0.f, 0.f};
  f32x4 acc[8][4];
#pragma unroll
  for (int m = 0; m < 8; ++m)
#pragma unroll
    for (int n = 0; n < 4; ++n) acc[m][n] = zero;

  float4 va[8];

  // prologue: A(0) reg-loads FIRST (for vmcnt order), then B(0),B(1) gload_lds.
  // vmcnt(4): A(0)+B(0) landed, B(1) in flight. exp+write A(0) -> buf0.
  LOADA(0);
  STB(0, 0, 0); STB(0, 1, 0);
  STB(1, 0, 1); STB(1, 1, 1);
  VMW(4);
  CVTA(0);
  LGKM0;
  SBAR;

  // 16 K-tiles: 7 unrolled pairs + tiles 14,15
  for (int p = 0; p < 7; ++p) {
    KTILE(0, 1, 2, 4)
    KTILE(1, 2, 3, 4)
    pLA4 += 32;   // 2 tiles * 64 f32 = 32 float4
    pgB  += 128;  // 2 tiles * 64 bf16
  }
  KTILE(0, 1, -1, 0)    // tile 14: load+stage A(15); drain everything
  KTILE(1, -1, -1, -1)  // tile 15

  // epilogue: out = log(acc). D row = 4*(l>>4)+r (+16/mf), col = l&15 (+16/nf)
  const int c0 = bn * 256 + wc * 64 + (l & 15);
  const int r0 = bm * 256 + wr * 128 + (l >> 4) * 4;
#pragma unroll
  for (int mf = 0; mf < 8; ++mf) {
#pragma unroll
    for (int r = 0; r < 4; ++r) {
      const int row = r0 + mf * 16 + r;
      float* o = out + (size_t)row * NN_ + c0;
#pragma unroll
      for (int nf = 0; nf < 4; ++nf)
        __builtin_nontemporal_store(__logf(acc[mf][nf][r]), o + nf * 16);
    }
  }
}

extern "C" void kernel_launch(void* const* d_in, const int* in_sizes, int n_in,
                              void* d_out, int out_size, void* d_ws, size_t ws_size,
                              hipStream_t stream) {
  const float* log_alpha = (const float*)d_in[0];  // [16384,1024] f32
  const float* W         = (const float*)d_in[1];  // [1024,1024] f32
  float* out = (float*)d_out;                      // [16384,1024] f32

  uintptr_t ws = (uintptr_t)d_ws;
  bhalf* eA     = (bhalf*)(ws);                    // 2,097,152 B
  float* colLSE = (float*)(ws + 2097152);          //     4,096 B
  float* pM     = (float*)(ws + 2101248);          //   131,072 B
  float* pS     = (float*)(ws + 2232320);          //   131,072 B

  k_colpart<<<dim3(4, 32), 256, 0, stream>>>(W, pM, pS);
  k_colfin<<<4, 256, 0, stream>>>(pM, pS, colLSE);
  k_expA<<<NN_, 64, 0, stream>>>(W, colLSE, eA);
  k_gemm<<<(MB_ / 256) * (NN_ / 256), 512, 0, stream>>>(log_alpha, eA, out);
}

// Round 5
// 67.932 us; speedup vs baseline: 1.1975x; 1.1975x over previous
//
#include <hip/hip_runtime.h>
#include <hip/hip_bf16.h>
#include <stdint.h>

#define MB_ 16384
#define NN_ 1024
#define KK_ 1024

typedef __bf16 bhalf;
typedef __bf16 bhalf8 __attribute__((ext_vector_type(8)));
typedef __bf16 bhalf4 __attribute__((ext_vector_type(4)));
typedef float f32x4 __attribute__((ext_vector_type(4)));

typedef const __attribute__((address_space(1))) void* gas_ptr;
typedef __attribute__((address_space(3))) void* las_ptr;

__device__ __forceinline__ void gload_lds16(const void* g, void* l) {
  __builtin_amdgcn_global_load_lds((gas_ptr)g, (las_ptr)l, 16, 0, 0);
}

// ---------------- K1a: partial column max / sumexp (over rows, per column) ----------------
__global__ void k_colpart(const float* __restrict__ W,
                          float* __restrict__ pM, float* __restrict__ pS) {
  int col = blockIdx.x * 256 + threadIdx.x;
  int rc  = blockIdx.y;
  const float* p = W + (size_t)rc * 32 * NN_ + col;
  float v[32];
#pragma unroll
  for (int i = 0; i < 32; ++i) v[i] = p[(size_t)i * NN_];
  float m = v[0];
#pragma unroll
  for (int i = 1; i < 32; ++i) m = fmaxf(m, v[i]);
  float s = 0.f;
#pragma unroll
  for (int i = 0; i < 32; ++i) s += __expf(v[i] - m);
  pM[rc * NN_ + col] = m;
  pS[rc * NN_ + col] = s;
}

// ---------------- K1b: combine partials -> colLSE ----------------
__global__ void k_colfin(const float* __restrict__ pM, const float* __restrict__ pS,
                         float* __restrict__ colLSE) {
  int col = blockIdx.x * 256 + threadIdx.x;
  float m = -1e30f;
#pragma unroll
  for (int i = 0; i < 32; ++i) m = fmaxf(m, pM[i * NN_ + col]);
  float s = 0.f;
#pragma unroll
  for (int i = 0; i < 32; ++i) s += pS[i * NN_ + col] * __expf(pM[i * NN_ + col] - m);
  colLSE[col] = m + __logf(s);
}

// ---------------- K2: eA[i,k] = exp(W[i,k]-colLSE[k]) ----------------
__global__ void k_expA(const float* __restrict__ W, const float* __restrict__ colLSE,
                       bhalf* __restrict__ eA) {
  int i = blockIdx.x;
  int l = threadIdx.x;
  const float4* row = (const float4*)(W + (size_t)i * NN_);
  const float4* cls = (const float4*)colLSE;
#pragma unroll
  for (int t = 0; t < 4; ++t) {
    float4 wv = row[t * 64 + l];
    float4 cv = cls[t * 64 + l];
    bhalf4 o;
    o[0] = (bhalf)__expf(wv.x - cv.x);
    o[1] = (bhalf)__expf(wv.y - cv.y);
    o[2] = (bhalf)__expf(wv.z - cv.z);
    o[3] = (bhalf)__expf(wv.w - cv.w);
    *(bhalf4*)(eA + (size_t)i * NN_ + t * 256 + l * 4) = o;
  }
}

// ---------------- GEMM: out[b,i] = log( sum_k exp(la[b,k]) * eA[i,k] ) ----------------
// 256x256 tile, BK=64, 512 thr (8 waves 2Mx4N). Round-2 schedule; A-staging fused:
//   q0: 8x COALESCED global_load_dwordx4 of la(t+1) f32 (rows r*32+(tid>>4), 16B per lane)
//   q1/q2: B(t+2) via global_load_lds (pre-swizzled source, linear dest)
//   post-MFMA(q3): vmcnt(4) drains A(t+1)+B(t+1), keeps B(t+2); exp+pack bf16 ->
//   8x ds_write_b64 at constant swizzled offsets into buf^1.
// LDS: A dbuf [0,64K), B dbuf [64K,128K).

#define VMW(N)  asm volatile("s_waitcnt vmcnt(" #N ")" ::: "memory")
#define LGKM0   asm volatile("s_waitcnt lgkmcnt(0)" ::: "memory")
#define HINT8   asm volatile("s_waitcnt lgkmcnt(8)" ::: "memory")
#define SBAR    __builtin_amdgcn_s_barrier()
#define SCB0    __builtin_amdgcn_sched_barrier(0)
#define NOPS    ((void)0)

#define STB(BUF, H, TOFF) do {                                                \
    const bhalf* g_ = pgB + (H) * 131072 + (TOFF) * 64;                       \
    unsigned char* d_ = lds + 65536 + (BUF) * 32768 + (H) * 16384 + tid * 16; \
    gload_lds16(g_, d_); gload_lds16(g_ + 65536, d_ + 8192); } while (0)

// coalesced: round r_, lanes 0..15 cover one row's 256B; rows r_*32+(tid>>4)
#define LOADA(TOFF) do {                                                      \
    _Pragma("unroll")                                                         \
    for (int r_ = 0; r_ < 8; ++r_) va[r_] = pLA4[r_ * 8192 + (TOFF) * 16];    \
  } while (0)

// exp + pack to bf16, 8x ds_write_b64 at constant swizzled offsets
#define CVTA(BUF) do {                                                        \
    unsigned char* d_ = dA_base + (BUF) * 32768;                              \
    _Pragma("unroll")                                                         \
    for (int r_ = 0; r_ < 8; ++r_) {                                          \
      float4 u_ = va[r_];                                                     \
      bhalf4 o_;                                                              \
      o_[0] = (bhalf)__expf(u_.x); o_[1] = (bhalf)__expf(u_.y);               \
      o_[2] = (bhalf)__expf(u_.z); o_[3] = (bhalf)__expf(u_.w);               \
      *(bhalf4*)(d_ + (r_ & 3) * 4096 + (r_ >> 2) * 16384) = o_;              \
    } } while (0)

#define DS_AF(BUF, Q)                                                         \
  af[0][0] = *(const bhalf8*)(pA0 + (BUF) * 32768 + (Q) * 4096);              \
  af[0][1] = *(const bhalf8*)(pA1 + (BUF) * 32768 + (Q) * 4096);              \
  af[1][0] = *(const bhalf8*)(pA0 + (BUF) * 32768 + (Q) * 4096 + 2048);       \
  af[1][1] = *(const bhalf8*)(pA1 + (BUF) * 32768 + (Q) * 4096 + 2048);

#define DS_BQ(BUF)                                                            \
  _Pragma("unroll")                                                           \
  for (int n_ = 0; n_ < 4; ++n_) {                                            \
    bq[n_][0] = *(const bhalf8*)(pB0 + (BUF) * 32768 + n_ * 2048);            \
    bq[n_][1] = *(const bhalf8*)(pB1 + (BUF) * 32768 + n_ * 2048);            \
  }

#define MFMA8(Q)                                                              \
  __builtin_amdgcn_s_setprio(1);                                              \
  _Pragma("unroll")                                                           \
  for (int m_ = 0; m_ < 2; ++m_)                                              \
    _Pragma("unroll")                                                         \
    for (int n_ = 0; n_ < 4; ++n_)                                            \
      _Pragma("unroll")                                                       \
      for (int kk_ = 0; kk_ < 2; ++kk_)                                       \
        acc[2 * (Q) + m_][n_] = __builtin_amdgcn_mfma_f32_16x16x32_bf16(      \
            af[m_][kk_], bq[n_][kk_], acc[2 * (Q) + m_][n_], 0, 0, 0);        \
  __builtin_amdgcn_s_setprio(0);

#define HEAD  SCB0; SBAR; LGKM0; SCB0

// LT: A-load k-tile offset (rel to pLA4), -1 = none. BT: B-stage k-tile offset (rel to pgB).
// VMN: 4 / 0 / -1 post-MFMA(q3) wait. A(LT) is exp'd+written to buf BUF^1.
#define KTILE(BUF, LT, BT, VMN)                                               \
  {                                                                           \
    bhalf8 bq[4][2];                                                          \
    bhalf8 af[2][2];                                                          \
    DS_AF(BUF, 0) DS_BQ(BUF)                                                  \
    if ((LT) >= 0) LOADA(LT);                                                 \
    HINT8;                                                                    \
    HEAD; MFMA8(0) SBAR;                                                      \
    DS_AF(BUF, 1)                                                             \
    if ((BT) >= 0) STB(BUF, 0, BT);                                           \
    HEAD; MFMA8(1) SBAR;                                                      \
    DS_AF(BUF, 2)                                                             \
    if ((BT) >= 0) STB(BUF, 1, BT);                                           \
    HEAD; MFMA8(2) SBAR;                                                      \
    DS_AF(BUF, 3)                                                             \
    HEAD; MFMA8(3)                                                            \
    if ((VMN) == 4) VMW(4); else if ((VMN) == 0) VMW(0);                      \
    if ((LT) >= 0) { CVTA((BUF) ^ 1); LGKM0; }                                \
    SCB0; SBAR;                                                               \
  }

__global__ __launch_bounds__(512, 2) void k_gemm(const float* __restrict__ LA, // [M][K] f32
                                                 const bhalf* __restrict__ Bt, // eA [N][K]
                                                 float* __restrict__ out) {
  __shared__ __align__(16) unsigned char lds[131072];

  const int nwg = gridDim.x;              // 256, %8==0
  const int wg  = blockIdx.x;
  const int swz = (wg & 7) * (nwg >> 3) + (wg >> 3);
  const int bm = swz >> 2;                // 0..63
  const int bn = swz & 3;                 // 0..3

  const int tid = threadIdx.x;
  const int l = tid & 63;
  const int w = tid >> 6;
  const int wr = w >> 2;                  // 0..1 (M)
  const int wc = w & 3;                   // 0..3 (N)

  // B staging geometry (gload_lds, linear dest, pre-swizzled source)
  const int r8  = tid >> 3;
  const int kel = (((tid & 7) ^ (r8 & 7)) << 3);
  const bhalf* pgB = Bt + (size_t)(bn * 256 + r8) * KK_ + kel;

  // A fused staging: COALESCED reads. Round r_: row = r_*32 + (tid>>4), 16B chunk tid&15.
  const float4* pLA4 = (const float4*)(LA + (size_t)(bm * 256 + (tid >> 4)) * KK_) + (tid & 15);
  // write: row&7 == (tid>>4)&7 (round-invariant); chunk c=(tid&15)>>1, byte within = (tid&1)*8
  unsigned char* dA_base = lds + (tid >> 4) * 128 +
                           ((((tid & 15) >> 1) ^ ((tid >> 4) & 7)) << 4) + ((tid & 1) << 3);

  // loop-invariant LDS read bases (fragment row % 8 == l % 8)
  const int kx  = 16 * (l >> 4);
  const int x16 = (l & 7) << 4;
  const int kx0 = kx ^ x16;
  const int kx1 = (64 + kx) ^ x16;
  const unsigned char* pA0 = lds + wr * 16384 + (l & 15) * 128 + kx0;
  const unsigned char* pA1 = lds + wr * 16384 + (l & 15) * 128 + kx1;
  const unsigned char* pB0 = lds + 65536 + (wc >> 1) * 16384 + ((wc & 1) * 64 + (l & 15)) * 128 + kx0;
  const unsigned char* pB1 = lds + 65536 + (wc >> 1) * 16384 + ((wc & 1) * 64 + (l & 15)) * 128 + kx1;

  f32x4 zero = {0.f, 0.f, 0.f, 0.f};
  f32x4 acc[8][4];
#pragma unroll
  for (int m = 0; m < 8; ++m)
#pragma unroll
    for (int n = 0; n < 4; ++n) acc[m][n] = zero;

  float4 va[8];

  // prologue: A(0) regs, B(0), B(1). vmcnt(8): A(0) landed -> cvt to buf0.
  // vmcnt(4): B(0) landed, B(1) stays in flight.
  LOADA(0);
  STB(0, 0, 0); STB(0, 1, 0);
  STB(1, 0, 1); STB(1, 1, 1);
  VMW(8);
  CVTA(0);
  VMW(4);
  LGKM0;
  SBAR;

  // 16 K-tiles: 7 unrolled pairs + tiles 14,15
  for (int p = 0; p < 7; ++p) {
    KTILE(0, 1, 2, 4)
    KTILE(1, 2, 3, 4)
    pLA4 += 32;   // 2 tiles * 16 float4
    pgB  += 128;  // 2 tiles * 64 bf16
  }
  KTILE(0, 1, -1, 0)    // tile 14: load A(15); drain everything; cvt A(15)->buf1
  KTILE(1, -1, -1, -1)  // tile 15

  // epilogue: out = log(acc). D row = 4*(l>>4)+r (+16/mf), col = l&15 (+16/nf)
  const int c0 = bn * 256 + wc * 64 + (l & 15);
  const int r0 = bm * 256 + wr * 128 + (l >> 4) * 4;
#pragma unroll
  for (int mf = 0; mf < 8; ++mf) {
#pragma unroll
    for (int r = 0; r < 4; ++r) {
      const int row = r0 + mf * 16 + r;
      float* o = out + (size_t)row * NN_ + c0;
#pragma unroll
      for (int nf = 0; nf < 4; ++nf)
        __builtin_nontemporal_store(__logf(acc[mf][nf][r]), o + nf * 16);
    }
  }
}

extern "C" void kernel_launch(void* const* d_in, const int* in_sizes, int n_in,
                              void* d_out, int out_size, void* d_ws, size_t ws_size,
                              hipStream_t stream) {
  const float* log_alpha = (const float*)d_in[0];  // [16384,1024] f32
  const float* W         = (const float*)d_in[1];  // [1024,1024] f32
  float* out = (float*)d_out;                      // [16384,1024] f32

  uintptr_t ws = (uintptr_t)d_ws;
  bhalf* eA     = (bhalf*)(ws);                    // 2,097,152 B
  float* colLSE = (float*)(ws + 2097152);          //     4,096 B
  float* pM     = (float*)(ws + 2101248);          //   131,072 B
  float* pS     = (float*)(ws + 2232320);          //   131,072 B

  k_colpart<<<dim3(4, 32), 256, 0, stream>>>(W, pM, pS);
  k_colfin<<<4, 256, 0, stream>>>(pM, pS, colLSE);
  k_expA<<<NN_, 64, 0, stream>>>(W, colLSE, eA);
  k_gemm<<<(MB_ / 256) * (NN_ / 256), 512, 0, stream>>>(log_alpha, eA, out);
}

// Round 6
// 61.468 us; speedup vs baseline: 1.3234x; 1.1052x over previous
//
#include <hip/hip_runtime.h>
#include <hip/hip_bf16.h>
#include <stdint.h>

#define MB_ 16384
#define NN_ 1024
#define KK_ 1024

typedef __bf16 bhalf;
typedef __bf16 bhalf8 __attribute__((ext_vector_type(8)));
typedef __bf16 bhalf4 __attribute__((ext_vector_type(4)));
typedef float f32x4 __attribute__((ext_vector_type(4)));

typedef const __attribute__((address_space(1))) void* gas_ptr;
typedef __attribute__((address_space(3))) void* las_ptr;

__device__ __forceinline__ void gload_lds16(const void* g, void* l) {
  __builtin_amdgcn_global_load_lds((gas_ptr)g, (las_ptr)l, 16, 0, 0);
}

// ---------------- K1a: partial column max / sumexp (over rows, per column) ----------------
__global__ void k_colpart(const float* __restrict__ W,
                          float* __restrict__ pM, float* __restrict__ pS) {
  int col = blockIdx.x * 256 + threadIdx.x;
  int rc  = blockIdx.y;
  const float* p = W + (size_t)rc * 32 * NN_ + col;
  float v[32];
#pragma unroll
  for (int i = 0; i < 32; ++i) v[i] = p[(size_t)i * NN_];
  float m = v[0];
#pragma unroll
  for (int i = 1; i < 32; ++i) m = fmaxf(m, v[i]);
  float s = 0.f;
#pragma unroll
  for (int i = 0; i < 32; ++i) s += __expf(v[i] - m);
  pM[rc * NN_ + col] = m;
  pS[rc * NN_ + col] = s;
}

// ---------------- K1b: combine partials -> colLSE ----------------
__global__ void k_colfin(const float* __restrict__ pM, const float* __restrict__ pS,
                         float* __restrict__ colLSE) {
  int col = blockIdx.x * 256 + threadIdx.x;
  float m = -1e30f;
#pragma unroll
  for (int i = 0; i < 32; ++i) m = fmaxf(m, pM[i * NN_ + col]);
  float s = 0.f;
#pragma unroll
  for (int i = 0; i < 32; ++i) s += pS[i * NN_ + col] * __expf(pM[i * NN_ + col] - m);
  colLSE[col] = m + __logf(s);
}

// ---------------- K2: eA[i,k] = exp(W[i,k]-colLSE[k]) ----------------
__global__ void k_expA(const float* __restrict__ W, const float* __restrict__ colLSE,
                       bhalf* __restrict__ eA) {
  int i = blockIdx.x;
  int l = threadIdx.x;
  const float4* row = (const float4*)(W + (size_t)i * NN_);
  const float4* cls = (const float4*)colLSE;
#pragma unroll
  for (int t = 0; t < 4; ++t) {
    float4 wv = row[t * 64 + l];
    float4 cv = cls[t * 64 + l];
    bhalf4 o;
    o[0] = (bhalf)__expf(wv.x - cv.x);
    o[1] = (bhalf)__expf(wv.y - cv.y);
    o[2] = (bhalf)__expf(wv.z - cv.z);
    o[3] = (bhalf)__expf(wv.w - cv.w);
    *(bhalf4*)(eA + (size_t)i * NN_ + t * 256 + l * 4) = o;
  }
}

// ---------------- GEMM: out[b,i] = log( sum_k exp(la[b,k]) * eA[i,k] ) ----------------
// 256x256 tile, BK=64, 512 thr (8 waves 2Mx4N). Fused A-staging, cvt SPLIT across phases:
//   q0: 8x coalesced dwordx4 la(t+1) + 12 ds_reads
//   q1: B(t+2)h0 stage; post-MFMA: vmcnt(6) -> cvt chunks 0-3 (A rows 0..127)
//   q2: B(t+2)h1 stage; post-MFMA: vmcnt(4) -> cvt chunks 4-7 (A rows 128..255)
//   q3: clean (HEAD lgkmcnt(0) drains the cvt ds_writes before the publishing barrier)
// In-flight at q3 end: B(t+2) (4 loads) -- never drained to 0 mid-loop.
// LDS: A dbuf [0,64K), B dbuf [64K,128K).

#define VMW(N)  asm volatile("s_waitcnt vmcnt(" #N ")" ::: "memory")
#define LGKM0   asm volatile("s_waitcnt lgkmcnt(0)" ::: "memory")
#define HINT8   asm volatile("s_waitcnt lgkmcnt(8)" ::: "memory")
#define SBAR    __builtin_amdgcn_s_barrier()
#define SCB0    __builtin_amdgcn_sched_barrier(0)

#define STB(BUF, H, TOFF) do {                                                \
    const bhalf* g_ = pgB + (H) * 131072 + (TOFF) * 64;                       \
    unsigned char* d_ = lds + 65536 + (BUF) * 32768 + (H) * 16384 + tid * 16; \
    gload_lds16(g_, d_); gload_lds16(g_ + 65536, d_ + 8192); } while (0)

// coalesced: round r_, lanes 0..15 cover one row's 256B; rows r_*32+(tid>>4)
#define LOADA(TOFF) do {                                                      \
    _Pragma("unroll")                                                         \
    for (int r_ = 0; r_ < 8; ++r_) va[r_] = pLA4[r_ * 8192 + (TOFF) * 16];    \
  } while (0)

// exp + pack to bf16, 4x ds_write_b64 for chunk-half H (rounds 4H..4H+3)
#define CVTA_H(BUF, H) do {                                                   \
    unsigned char* d_ = dA_base + (BUF) * 32768 + (H) * 16384;                \
    _Pragma("unroll")                                                         \
    for (int j_ = 0; j_ < 4; ++j_) {                                          \
      float4 u_ = va[(H) * 4 + j_];                                           \
      bhalf4 o_;                                                              \
      o_[0] = (bhalf)__expf(u_.x); o_[1] = (bhalf)__expf(u_.y);               \
      o_[2] = (bhalf)__expf(u_.z); o_[3] = (bhalf)__expf(u_.w);               \
      *(bhalf4*)(d_ + j_ * 4096) = o_;                                        \
    } } while (0)

#define DS_AF(BUF, Q)                                                         \
  af[0][0] = *(const bhalf8*)(pA0 + (BUF) * 32768 + (Q) * 4096);              \
  af[0][1] = *(const bhalf8*)(pA1 + (BUF) * 32768 + (Q) * 4096);              \
  af[1][0] = *(const bhalf8*)(pA0 + (BUF) * 32768 + (Q) * 4096 + 2048);       \
  af[1][1] = *(const bhalf8*)(pA1 + (BUF) * 32768 + (Q) * 4096 + 2048);

#define DS_BQ(BUF)                                                            \
  _Pragma("unroll")                                                           \
  for (int n_ = 0; n_ < 4; ++n_) {                                            \
    bq[n_][0] = *(const bhalf8*)(pB0 + (BUF) * 32768 + n_ * 2048);            \
    bq[n_][1] = *(const bhalf8*)(pB1 + (BUF) * 32768 + n_ * 2048);            \
  }

#define MFMA8(Q)                                                              \
  __builtin_amdgcn_s_setprio(1);                                              \
  _Pragma("unroll")                                                           \
  for (int m_ = 0; m_ < 2; ++m_)                                              \
    _Pragma("unroll")                                                         \
    for (int n_ = 0; n_ < 4; ++n_)                                            \
      _Pragma("unroll")                                                       \
      for (int kk_ = 0; kk_ < 2; ++kk_)                                       \
        acc[2 * (Q) + m_][n_] = __builtin_amdgcn_mfma_f32_16x16x32_bf16(      \
            af[m_][kk_], bq[n_][kk_], acc[2 * (Q) + m_][n_], 0, 0, 0);        \
  __builtin_amdgcn_s_setprio(0);

#define HEAD  SCB0; SBAR; LGKM0; SCB0

// LT: A-load k-tile offset (rel to pLA4), -1 none. BT: B-stage k-tile offset, -1 none.
// VM1/VM2: post-MFMA(q1)/(q2) vmcnt values (6/4/0, -1 = none). cvt -> buf BUF^1.
#define KTILE(BUF, LT, BT, VM1, VM2)                                          \
  {                                                                           \
    bhalf8 bq[4][2];                                                          \
    bhalf8 af[2][2];                                                          \
    DS_AF(BUF, 0) DS_BQ(BUF)                                                  \
    if ((LT) >= 0) LOADA(LT);                                                 \
    HINT8;                                                                    \
    HEAD; MFMA8(0) SBAR;                                                      \
    DS_AF(BUF, 1)                                                             \
    if ((BT) >= 0) STB(BUF, 0, BT);                                           \
    HEAD; MFMA8(1)                                                            \
    if ((VM1) == 6) VMW(6); else if ((VM1) == 4) VMW(4);                      \
    else if ((VM1) == 0) VMW(0);                                              \
    if ((LT) >= 0) CVTA_H((BUF) ^ 1, 0);                                      \
    SCB0; SBAR;                                                               \
    DS_AF(BUF, 2)                                                             \
    if ((BT) >= 0) STB(BUF, 1, BT);                                           \
    HEAD; MFMA8(2)                                                            \
    if ((VM2) == 6) VMW(6); else if ((VM2) == 4) VMW(4);                      \
    else if ((VM2) == 0) VMW(0);                                              \
    if ((LT) >= 0) CVTA_H((BUF) ^ 1, 1);                                      \
    SCB0; SBAR;                                                               \
    DS_AF(BUF, 3)                                                             \
    HEAD; MFMA8(3) SBAR;                                                      \
  }

__global__ __launch_bounds__(512, 2) void k_gemm(const float* __restrict__ LA, // [M][K] f32
                                                 const bhalf* __restrict__ Bt, // eA [N][K]
                                                 float* __restrict__ out) {
  __shared__ __align__(16) unsigned char lds[131072];

  const int nwg = gridDim.x;              // 256, %8==0
  const int wg  = blockIdx.x;
  const int swz = (wg & 7) * (nwg >> 3) + (wg >> 3);
  const int bm = swz >> 2;                // 0..63
  const int bn = swz & 3;                 // 0..3

  const int tid = threadIdx.x;
  const int l = tid & 63;
  const int w = tid >> 6;
  const int wr = w >> 2;                  // 0..1 (M)
  const int wc = w & 3;                   // 0..3 (N)

  // B staging geometry (gload_lds, linear dest, pre-swizzled source)
  const int r8  = tid >> 3;
  const int kel = (((tid & 7) ^ (r8 & 7)) << 3);
  const bhalf* pgB = Bt + (size_t)(bn * 256 + r8) * KK_ + kel;

  // A fused staging: coalesced. Round r_: row = r_*32 + (tid>>4), 16B chunk tid&15.
  const float4* pLA4 = (const float4*)(LA + (size_t)(bm * 256 + (tid >> 4)) * KK_) + (tid & 15);
  // write: row&7 == (tid>>4)&7 (round-invariant); chunk c=(tid&15)>>1, byte = (tid&1)*8
  unsigned char* dA_base = lds + (tid >> 4) * 128 +
                           ((((tid & 15) >> 1) ^ ((tid >> 4) & 7)) << 4) + ((tid & 1) << 3);

  // loop-invariant LDS read bases (fragment row % 8 == l % 8)
  const int kx  = 16 * (l >> 4);
  const int x16 = (l & 7) << 4;
  const int kx0 = kx ^ x16;
  const int kx1 = (64 + kx) ^ x16;
  const unsigned char* pA0 = lds + wr * 16384 + (l & 15) * 128 + kx0;
  const unsigned char* pA1 = lds + wr * 16384 + (l & 15) * 128 + kx1;
  const unsigned char* pB0 = lds + 65536 + (wc >> 1) * 16384 + ((wc & 1) * 64 + (l & 15)) * 128 + kx0;
  const unsigned char* pB1 = lds + 65536 + (wc >> 1) * 16384 + ((wc & 1) * 64 + (l & 15)) * 128 + kx1;

  f32x4 zero = {0.f, 0.f, 0.f, 0.f};
  f32x4 acc[8][4];
#pragma unroll
  for (int m = 0; m < 8; ++m)
#pragma unroll
    for (int n = 0; n < 4; ++n) acc[m][n] = zero;

  float4 va[8];

  // prologue: A(0) regs, B(0), B(1). vmcnt(8): A(0) landed -> cvt both halves to buf0.
  // vmcnt(4): B(0) landed, B(1) stays in flight.
  LOADA(0);
  STB(0, 0, 0); STB(0, 1, 0);
  STB(1, 0, 1); STB(1, 1, 1);
  VMW(8);
  CVTA_H(0, 0); CVTA_H(0, 1);
  VMW(4);
  LGKM0;
  SBAR;

  // 16 K-tiles: 7 unrolled pairs + tiles 14,15
  for (int p = 0; p < 7; ++p) {
    KTILE(0, 1, 2, 6, 4)
    KTILE(1, 2, 3, 6, 4)
    pLA4 += 32;   // 2 tiles * 16 float4
    pgB  += 128;  // 2 tiles * 64 bf16
  }
  KTILE(0, 1, -1, 4, 0)       // tile 14: load A(15); drain; cvt A(15)->buf1
  KTILE(1, -1, -1, -1, -1)    // tile 15

  // epilogue: out = log(acc). D row = 4*(l>>4)+r (+16/mf), col = l&15 (+16/nf)
  const int c0 = bn * 256 + wc * 64 + (l & 15);
  const int r0 = bm * 256 + wr * 128 + (l >> 4) * 4;
#pragma unroll
  for (int mf = 0; mf < 8; ++mf) {
#pragma unroll
    for (int r = 0; r < 4; ++r) {
      const int row = r0 + mf * 16 + r;
      float* o = out + (size_t)row * NN_ + c0;
#pragma unroll
      for (int nf = 0; nf < 4; ++nf)
        o[nf * 16] = __logf(acc[mf][nf][r]);
    }
  }
}

extern "C" void kernel_launch(void* const* d_in, const int* in_sizes, int n_in,
                              void* d_out, int out_size, void* d_ws, size_t ws_size,
                              hipStream_t stream) {
  const float* log_alpha = (const float*)d_in[0];  // [16384,1024] f32
  const float* W         = (const float*)d_in[1];  // [1024,1024] f32
  float* out = (float*)d_out;                      // [16384,1024] f32

  uintptr_t ws = (uintptr_t)d_ws;
  bhalf* eA     = (bhalf*)(ws);                    // 2,097,152 B
  float* colLSE = (float*)(ws + 2097152);          //     4,096 B
  float* pM     = (float*)(ws + 2101248);          //   131,072 B
  float* pS     = (float*)(ws + 2232320);          //   131,072 B

  k_colpart<<<dim3(4, 32), 256, 0, stream>>>(W, pM, pS);
  k_colfin<<<4, 256, 0, stream>>>(pM, pS, colLSE);
  k_expA<<<NN_, 64, 0, stream>>>(W, colLSE, eA);
  k_gemm<<<(MB_ / 256) * (NN_ / 256), 512, 0, stream>>>(log_alpha, eA, out);
}